// Round 1
// 829.883 us; speedup vs baseline: 1.0255x; 1.0255x over previous
//
#include <hip/hip_runtime.h>

// Problem constants (match reference setup_inputs)
#define NPOL   2
#define NANT   64
#define NBL    2016
#define NT     64
#define NF     256

constexpr int  TF     = NT * NF;              // 16384 points per (pol-plane, baseline)
constexpr int  TF4    = TF / 4;               // 4096 float4 chunks per baseline
constexpr long VPLANE = (long)NBL * TF;       // stride between (b,c) pol planes of V_m / out
constexpr long JPLANE = (long)NANT * TF;      // stride between (a,b) pol planes of jones
constexpr int  BLOCK  = 256;
constexpr int  NGRID  = NBL * TF4 / BLOCK;    // 32256 blocks (exact)
constexpr int  NXCD   = 8;
constexpr int  GPX    = NGRID / NXCD;         // 4032 blocks per XCD (exact)

// native clang vector type so __builtin_nontemporal_* applies cleanly
typedef float f4 __attribute__((ext_vector_type(4)));

__device__ __forceinline__ f4 f4_mul(f4 a, f4 b) {
    f4 r;
    r.x = a.x * b.x; r.y = a.y * b.y; r.z = a.z * b.z; r.w = a.w * b.w;
    return r;
}
__device__ __forceinline__ f4 f4_fma(f4 a, f4 b, f4 c) {
    f4 r;
    r.x = fmaf(a.x, b.x, c.x); r.y = fmaf(a.y, b.y, c.y);
    r.z = fmaf(a.z, b.z, c.z); r.w = fmaf(a.w, b.w, c.w);
    return r;
}

__global__ __launch_bounds__(256) void jones_congruence_kernel(
    const float* __restrict__ V,     // (2,2,NBL,NT,NF)
    const float* __restrict__ J,     // (2,2,NANT,NT,NF)
    const int*   __restrict__ ant1,  // (NBL,)
    const int*   __restrict__ ant2,  // (NBL,)
    float*       __restrict__ out)   // (2,2,NBL,NT,NF)
{
    // XCD-contiguous swizzle: hardware round-robins blockIdx across the 8 XCDs,
    // so map bid -> wid such that each XCD gets a CONTIGUOUS range of work ids.
    // Work order: baseline-fast, r-chunk-slow. Each XCD then owns exactly
    // 2 of the 16 r-chunks for ALL baselines -> its J working set is
    // 64 ants x 4 pol-planes x 8 KB = 2 MB, resident in its 4 MB L2.
    const int bid = blockIdx.x;
    const int wid = (bid & (NXCD - 1)) * GPX + (bid >> 3);   // bijective: 32256 % 8 == 0

    const int c = wid / NBL;              // r-chunk index, 0..15 (256 float4 each)
    const int n = wid - c * NBL;          // baseline, 0..2015
    const int r4 = c * BLOCK + (int)threadIdx.x;   // float4 index within a plane

    const long base_v  = (long)n * TF + (long)r4 * 4;
    const int  a1      = ant1[n];
    const int  a2      = ant2[n];
    const long base_j1 = (long)a1 * TF + (long)r4 * 4;
    const long base_j2 = (long)a2 * TF + (long)r4 * 4;

    // V is touched exactly once -> nontemporal (don't evict L2-resident J)
    const f4 v00 = __builtin_nontemporal_load((const f4*)(V + 0 * VPLANE + base_v));
    const f4 v01 = __builtin_nontemporal_load((const f4*)(V + 1 * VPLANE + base_v));
    const f4 v10 = __builtin_nontemporal_load((const f4*)(V + 2 * VPLANE + base_v));
    const f4 v11 = __builtin_nontemporal_load((const f4*)(V + 3 * VPLANE + base_v));

    // J is reused ~63x across baselines -> normal cached loads (L2-resident)
    const f4 j1_00 = *(const f4*)(J + 0 * JPLANE + base_j1);
    const f4 j1_01 = *(const f4*)(J + 1 * JPLANE + base_j1);
    const f4 j1_10 = *(const f4*)(J + 2 * JPLANE + base_j1);
    const f4 j1_11 = *(const f4*)(J + 3 * JPLANE + base_j1);

    const f4 j2_00 = *(const f4*)(J + 0 * JPLANE + base_j2);
    const f4 j2_01 = *(const f4*)(J + 1 * JPLANE + base_j2);
    const f4 j2_10 = *(const f4*)(J + 2 * JPLANE + base_j2);
    const f4 j2_11 = *(const f4*)(J + 3 * JPLANE + base_j2);

    // W = J1 @ V : W[a][c] = J1[a][0]*V[0][c] + J1[a][1]*V[1][c]
    // (identical op ordering to the previous kernel: absmax stayed 0.0)
    const f4 w00 = f4_fma(j1_01, v10, f4_mul(j1_00, v00));
    const f4 w01 = f4_fma(j1_01, v11, f4_mul(j1_00, v01));
    const f4 w10 = f4_fma(j1_11, v10, f4_mul(j1_10, v00));
    const f4 w11 = f4_fma(j1_11, v11, f4_mul(j1_10, v01));

    // Out[a][d] = W[a][0]*J2[d][0] + W[a][1]*J2[d][1]
    const f4 o00 = f4_fma(w01, j2_01, f4_mul(w00, j2_00));
    const f4 o01 = f4_fma(w01, j2_11, f4_mul(w00, j2_10));
    const f4 o10 = f4_fma(w11, j2_01, f4_mul(w10, j2_00));
    const f4 o11 = f4_fma(w11, j2_11, f4_mul(w10, j2_10));

    // out is written exactly once -> nontemporal stores
    __builtin_nontemporal_store(o00, (f4*)(out + 0 * VPLANE + base_v));
    __builtin_nontemporal_store(o01, (f4*)(out + 1 * VPLANE + base_v));
    __builtin_nontemporal_store(o10, (f4*)(out + 2 * VPLANE + base_v));
    __builtin_nontemporal_store(o11, (f4*)(out + 3 * VPLANE + base_v));
}

extern "C" void kernel_launch(void* const* d_in, const int* in_sizes, int n_in,
                              void* d_out, int out_size, void* d_ws, size_t ws_size,
                              hipStream_t stream) {
    const float* V    = (const float*)d_in[0];
    const float* J    = (const float*)d_in[1];
    const int*   ant1 = (const int*)d_in[2];
    const int*   ant2 = (const int*)d_in[3];
    float*       out  = (float*)d_out;

    jones_congruence_kernel<<<NGRID, BLOCK, 0, stream>>>(V, J, ant1, ant2, out);
}